// Round 6
// baseline (231.586 us; speedup 1.0000x reference)
//
#include <hip/hip_runtime.h>

#define ORDER 1024
#define NCOEF 1025
#define BATCH 8192

typedef float v2 __attribute__((ext_vector_type(2)));
typedef float v4f __attribute__((ext_vector_type(4)));

// lane i reads lane i-1; lane 0 reads 0 (bound_ctrl). Single VALU instr.
__device__ __forceinline__ float wave_shr1(float v) {
    int r = __builtin_amdgcn_update_dpp(0, __float_as_int(v),
                                        0x138 /*wave_shr:1*/, 0xf, 0xf, true);
    return __int_as_float(r);
}

// readfirstlane is int(int): bitcast round-trip, NOT value conversion.
__device__ __forceinline__ float sgpr_f32(float v) {
    return __int_as_float(__builtin_amdgcn_readfirstlane(__float_as_int(v)));
}

// Lane-local coefficient bank, stride-9 pairing on the 17-coeff cycle:
//   p[m] = (c_m, c_{m+9})  for m=0..7 ; x = (dpp scratch, c_8)
// Shift-by-1 source of p[m] is p[m-1] (aligned -> v_pk_fma_f32).
// IN-PLACE update (no ping-pong): descending m reads old p[m-1] before it
// is overwritten; new c_8 computed into a temp before p[7] is touched.
struct Bank { v2 p[8]; v2 x; };

__device__ __forceinline__ void step(Bank& A, float nx) {
    v2 nxp; nxp.x = nx; nxp.y = nx;
    const float t = wave_shr1(A.p[7].y);                 // old c_16 of prev lane
    const float c8new = __builtin_fmaf(nx, A.p[7].x, A.x.y); // old c_7, old c_8
    v2 xold; xold.x = t; xold.y = A.x.y;                 // (c_{-1}, c_8) old
#pragma unroll
    for (int m = 7; m >= 1; --m)
        A.p[m] = __builtin_elementwise_fma(nxp, A.p[m - 1], A.p[m]);
    A.p[0] = __builtin_elementwise_fma(nxp, xold, A.p[0]);
    A.x.y = c8new;
}

__global__ __launch_bounds__(64) void r2p_kernel(const float* __restrict__ x,
                                                 float* __restrict__ out) {
    const int lane = threadIdx.x & 63;
    int row = (int)blockIdx.x;
    row = __builtin_amdgcn_readfirstlane(row);

    const float* __restrict__ xr = x + (size_t)row * ORDER;
    float* __restrict__ orow = out + (size_t)row * NCOEF;

    Bank A;
#pragma unroll
    for (int m = 0; m < 8; ++m) { A.p[m].x = 0.0f; A.p[m].y = 0.0f; }
    A.x.x = 0.0f; A.x.y = 0.0f;
    if (lane == 0) A.p[0].x = 1.0f;   // c_0 = 1: empty product

    v4f xv = *(const v4f*)(xr);
    for (int i = 0; i < ORDER; i += 4) {
        const int nexti = (i + 4 < ORDER) ? i + 4 : i;  // uniform
        v4f xn = *(const v4f*)(xr + nexti);             // prefetch next group

        step(A, -sgpr_f32(xv.x));
        step(A, -sgpr_f32(xv.y));
        step(A, -sgpr_f32(xv.z));
        step(A, -sgpr_f32(xv.w));

        xv = xn;
    }

    // Store: k = 17*lane + j ; j=0..7 -> p[j].lo, j=8 -> x.hi, j=9..16 -> p[j-9].hi
#pragma unroll
    for (int j = 0; j < 8; ++j) {
        const int k = lane * 17 + j;
        if (k < NCOEF) orow[k] = A.p[j].x;
    }
    {
        const int k = lane * 17 + 8;
        if (k < NCOEF) orow[k] = A.x.y;
    }
#pragma unroll
    for (int j = 9; j < 17; ++j) {
        const int k = lane * 17 + j;
        if (k < NCOEF) orow[k] = A.p[j - 9].y;
    }
}

extern "C" void kernel_launch(void* const* d_in, const int* in_sizes, int n_in,
                              void* d_out, int out_size, void* d_ws, size_t ws_size,
                              hipStream_t stream) {
    const float* x = (const float*)d_in[0];
    float* out = (float*)d_out;
    dim3 grid(BATCH);   // one 64-lane wave per row
    dim3 block(64);
    hipLaunchKernelGGL(r2p_kernel, grid, block, 0, stream, x, out);
}

// Round 7
// 227.031 us; speedup vs baseline: 1.0201x; 1.0201x over previous
//
#include <hip/hip_runtime.h>

#define ORDER 1024
#define NCOEF 1025
#define BATCH 8192

typedef float v2 __attribute__((ext_vector_type(2)));
typedef float v8sf __attribute__((ext_vector_type(8)));

// lane i reads lane i-1; lane 0 reads 0 (bound_ctrl). Single VALU instr.
__device__ __forceinline__ float wave_shr1(float v) {
    int r = __builtin_amdgcn_update_dpp(0, __float_as_int(v),
                                        0x138 /*wave_shr:1*/, 0xf, 0xf, true);
    return __int_as_float(r);
}

// 8 roots -> SGPRs on the scalar pipe (no VALU, no vmcnt). The wait is a
// separate asm tied to the destination regs so uses can't be hoisted above it.
__device__ __forceinline__ v8sf s_load8(const float* p) {
    v8sf r;
    asm volatile("s_load_dwordx8 %0, %1, 0x0" : "=s"(r) : "s"(p));
    return r;
}
__device__ __forceinline__ void s_wait8(v8sf& r) {
    asm volatile("s_waitcnt lgkmcnt(0)" : "+s"(r));
}

// Lane-local coefficient bank, stride-9 pairing on the 17-coeff cycle:
//   p[m] = (c_m, c_{m+9})  for m=0..7 ; x = (dpp scratch, c_8)
// Shift-by-1 source of p[m] is p[m-1] (aligned -> v_pk_fma_f32).
// IN-PLACE update: descending m reads old p[m-1] before overwrite; new c_8
// computed into a temp before p[7] is touched.
struct Bank { v2 p[8]; v2 x; };

__device__ __forceinline__ void step(Bank& A, float nx) {
    v2 nxp; nxp.x = nx; nxp.y = nx;
    const float t = wave_shr1(A.p[7].y);                     // prev lane old c_16
    const float c8new = __builtin_fmaf(nx, A.p[7].x, A.x.y); // old c_7, old c_8
    v2 xold; xold.x = t; xold.y = A.x.y;                     // (c_{-1}, c_8) old
#pragma unroll
    for (int m = 7; m >= 1; --m)
        A.p[m] = __builtin_elementwise_fma(nxp, A.p[m - 1], A.p[m]);
    A.p[0] = __builtin_elementwise_fma(nxp, xold, A.p[0]);
    A.x.y = c8new;
}

__global__ __launch_bounds__(256) void r2p_kernel(const float* __restrict__ x,
                                                  float* __restrict__ out) {
    const int wave = threadIdx.x >> 6;
    const int lane = threadIdx.x & 63;
    int row = (int)blockIdx.x * 4 + wave;
    row = __builtin_amdgcn_readfirstlane(row);   // wave-uniform -> scalar math

    const float* __restrict__ xr = x + (size_t)row * ORDER;
    float* __restrict__ orow = out + (size_t)row * NCOEF;

    Bank A;
#pragma unroll
    for (int m = 0; m < 8; ++m) { A.p[m].x = 0.0f; A.p[m].y = 0.0f; }
    A.x.x = 0.0f; A.x.y = 0.0f;
    if (lane == 0) A.p[0].x = 1.0f;   // c_0 = 1: empty product

    // Root stream entirely on the scalar pipe, double-buffered one group
    // (8 steps ~ 300 issue-cyc) ahead: SMEM latency covered by own work +
    // 7 co-resident waves; zero VMEM waits in the loop.
    v8sf cur = s_load8(xr);
    s_wait8(cur);
    for (int i = 0; i < ORDER; i += 8) {
        const int nextoff = (i + 8 < ORDER) ? (i + 8) : i;   // uniform, SALU
        v8sf nxt = s_load8(xr + nextoff);

        step(A, -cur.s0);
        step(A, -cur.s1);
        step(A, -cur.s2);
        step(A, -cur.s3);
        step(A, -cur.s4);
        step(A, -cur.s5);
        step(A, -cur.s6);
        step(A, -cur.s7);

        s_wait8(nxt);
        cur = nxt;    // SALU moves, overlap with VALU
    }

    // Store: k = 17*lane + j ; j=0..7 -> p[j].lo, j=8 -> x.hi, j=9..16 -> p[j-9].hi
#pragma unroll
    for (int j = 0; j < 8; ++j) {
        const int k = lane * 17 + j;
        if (k < NCOEF) orow[k] = A.p[j].x;
    }
    {
        const int k = lane * 17 + 8;
        if (k < NCOEF) orow[k] = A.x.y;
    }
#pragma unroll
    for (int j = 9; j < 17; ++j) {
        const int k = lane * 17 + j;
        if (k < NCOEF) orow[k] = A.p[j - 9].y;
    }
}

extern "C" void kernel_launch(void* const* d_in, const int* in_sizes, int n_in,
                              void* d_out, int out_size, void* d_ws, size_t ws_size,
                              hipStream_t stream) {
    const float* x = (const float*)d_in[0];
    float* out = (float*)d_out;
    dim3 grid(BATCH / 4);  // 4 waves (rows) per 256-thread block
    dim3 block(256);
    hipLaunchKernelGGL(r2p_kernel, grid, block, 0, stream, x, out);
}